// Round 2
// baseline (796.327 us; speedup 1.0000x reference)
//
#include <hip/hip_runtime.h>
#include <cstdint>

typedef uint16_t u16;
typedef __attribute__((ext_vector_type(8))) short bf16x8;
typedef __attribute__((ext_vector_type(4))) float f32x4;

#define EPSBN 1e-5f

__device__ __forceinline__ float bf2f(u16 h) {
  return __uint_as_float(((unsigned)h) << 16);
}
__device__ __forceinline__ u16 f2bf(float f) {
  unsigned u = __float_as_uint(f);
  unsigned r = u + 0x7fffu + ((u >> 16) & 1u);
  return (u16)(r >> 16);
}

// ---------------------------------------------------------------------------
// K0: split W5 (fp32) into bf16 hi/lo arrays; fold BN scale/shift for L1..L4.
// Wf: [0..320) = scale (L1:0-63, L2:64-127, L3:128-191, L4:192-319),
//     [320..640) = shift, same channel mapping.
// ---------------------------------------------------------------------------
__global__ void k0_prep(const float* __restrict__ W5,
                        const float* g1, const float* b1, const float* m1, const float* v1,
                        const float* g2, const float* b2, const float* m2, const float* v2,
                        const float* g3, const float* b3, const float* m3, const float* v3,
                        const float* g4, const float* b4, const float* m4, const float* v4,
                        u16* __restrict__ W5h, u16* __restrict__ W5l,
                        float* __restrict__ Wf)
{
  int idx = blockIdx.x * 256 + threadIdx.x;
  if (idx < 131072) {
    float w = W5[idx];
    u16 hi = f2bf(w);
    float e = w - bf2f(hi);
    W5h[idx] = hi;
    W5l[idx] = f2bf(e);
  } else {
    int j = idx - 131072;
    if (j < 320) {
      const float *g, *bb, *mm, *vv; int ch;
      if (j < 64)       { g = g1; bb = b1; mm = m1; vv = v1; ch = j;       }
      else if (j < 128) { g = g2; bb = b2; mm = m2; vv = v2; ch = j - 64;  }
      else if (j < 192) { g = g3; bb = b3; mm = m3; vv = v3; ch = j - 128; }
      else              { g = g4; bb = b4; mm = m4; vv = v4; ch = j - 192; }
      float s = g[ch] / sqrtf(vv[ch] + EPSBN);
      Wf[j]       = s;
      Wf[320 + j] = bb[ch] - mm[ch] * s;
    }
  }
}

// ---------------------------------------------------------------------------
// K1: layers 1-4 per point (fp32 vector math). h lives in LDS column-major
// [buf][ch][thread] -> thread-private columns, no barriers, 2-way (free)
// bank pattern. Output h4 split into bf16 hi/lo, layout [point][128].
// ---------------------------------------------------------------------------
__global__ __launch_bounds__(128) void k1_conv(
    const float* __restrict__ x,
    const float* __restrict__ W1, const float* __restrict__ W2,
    const float* __restrict__ W3, const float* __restrict__ W4,
    const float* __restrict__ Wf,
    u16* __restrict__ H4a, u16* __restrict__ H4b)
{
  __shared__ float hb[2][64][128];   // exactly 64 KiB
  const int tid = threadIdx.x;
  const int pid = blockIdx.x * 128 + tid;
  const int b = pid >> 13, n = pid & 8191;

  const float x0 = x[(b * 3 + 0) * 8192 + n];
  const float x1 = x[(b * 3 + 1) * 8192 + n];
  const float x2 = x[(b * 3 + 2) * 8192 + n];

  // layer 1 (3 -> 64) -> buf0
  for (int o = 0; o < 64; ++o) {
    float c = W1[o * 3] * x0;
    c = fmaf(W1[o * 3 + 1], x1, c);
    c = fmaf(W1[o * 3 + 2], x2, c);
    hb[0][o][tid] = fmaxf(0.f, fmaf(c, Wf[o], Wf[320 + o]));
  }

  // layer 2 (64 -> 64): buf0 -> buf1
  {
    float hc[64];
    #pragma unroll
    for (int c = 0; c < 64; ++c) hc[c] = hb[0][c][tid];
    for (int o4 = 0; o4 < 16; ++o4) {
      float a[4] = {0.f, 0.f, 0.f, 0.f};
      #pragma unroll
      for (int j = 0; j < 64; ++j) {
        #pragma unroll
        for (int k = 0; k < 4; ++k)
          a[k] = fmaf(W2[(o4 * 4 + k) * 64 + j], hc[j], a[k]);
      }
      #pragma unroll
      for (int k = 0; k < 4; ++k) {
        int o = o4 * 4 + k;
        hb[1][o][tid] = fmaxf(0.f, fmaf(a[k], Wf[64 + o], Wf[384 + o]));
      }
    }
  }

  // layer 3 (64 -> 64): buf1 -> buf0
  {
    float hc[64];
    #pragma unroll
    for (int c = 0; c < 64; ++c) hc[c] = hb[1][c][tid];
    for (int o4 = 0; o4 < 16; ++o4) {
      float a[4] = {0.f, 0.f, 0.f, 0.f};
      #pragma unroll
      for (int j = 0; j < 64; ++j) {
        #pragma unroll
        for (int k = 0; k < 4; ++k)
          a[k] = fmaf(W3[(o4 * 4 + k) * 64 + j], hc[j], a[k]);
      }
      #pragma unroll
      for (int k = 0; k < 4; ++k) {
        int o = o4 * 4 + k;
        hb[0][o][tid] = fmaxf(0.f, fmaf(a[k], Wf[128 + o], Wf[448 + o]));
      }
    }
  }

  // layer 4 (64 -> 128): buf0 -> global, streamed in chunks of 8 channels
  {
    float hc[64];
    #pragma unroll
    for (int c = 0; c < 64; ++c) hc[c] = hb[0][c][tid];
    const size_t rowb = (size_t)pid * 128;
    for (int o8 = 0; o8 < 16; ++o8) {
      float v[8];
      #pragma unroll
      for (int jo = 0; jo < 8; ++jo) {
        int o = o8 * 8 + jo;
        float a = 0.f;
        #pragma unroll
        for (int j = 0; j < 64; ++j)
          a = fmaf(W4[o * 64 + j], hc[j], a);
        v[jo] = fmaxf(0.f, fmaf(a, Wf[192 + o], Wf[512 + o]));
      }
      uint4 hi4, lo4;
      unsigned hv[4], lv[4];
      #pragma unroll
      for (int p = 0; p < 4; ++p) {
        u16 h0 = f2bf(v[2 * p]);     float e0 = v[2 * p]     - bf2f(h0);
        u16 h1 = f2bf(v[2 * p + 1]); float e1 = v[2 * p + 1] - bf2f(h1);
        hv[p] = (unsigned)h0 | ((unsigned)f2bf(e0) == 0 ? 0u : 0u) | ((unsigned)h1 << 16);
        lv[p] = (unsigned)f2bf(e0) | ((unsigned)f2bf(e1) << 16);
      }
      hi4.x = hv[0]; hi4.y = hv[1]; hi4.z = hv[2]; hi4.w = hv[3];
      lo4.x = lv[0]; lo4.y = lv[1]; lo4.z = lv[2]; lo4.w = lv[3];
      *(uint4*)&H4a[rowb + o8 * 8] = hi4;
      *(uint4*)&H4b[rowb + o8 * 8] = lo4;
    }
  }
}

// ---------------------------------------------------------------------------
// K2: C[pt][ch] = sum_k h4[pt][k] * W5[ch][k] with 2x2 bf16 splits
// (Ah*Bh + Ah*Bl + Al*Bh). Block tile 128 pts x 128 ch, K=128.
// B-fragments load straight from global (W5 rows are fragment-contiguous).
// Per-channel running (max, first-idx); partials per point-split s.
// ---------------------------------------------------------------------------
__device__ __forceinline__ void k2_stage(
    u16* __restrict__ As, const u16* __restrict__ Hs,
    const int* __restrict__ sel, int b, int mb, int P, int tid)
{
  #pragma unroll
  for (int i = 0; i < 8; ++i) {
    int f = (i << 8) + tid;
    int p = f >> 4, kg = f & 15;
    int pt = mb + p;
    uint4 val; val.x = val.y = val.z = val.w = 0u;
    if (sel) {
      if (pt < P) {
        int n0 = sel[b * 600 + pt] & 8191;
        val = *(const uint4*)&Hs[(((size_t)b << 13) + n0) * 128 + (kg << 3)];
      }
    } else {
      val = *(const uint4*)&Hs[(((size_t)b << 13) + pt) * 128 + (kg << 3)];
    }
    *(uint4*)&As[p * 136 + (kg << 3)] = val;
  }
}

__global__ __launch_bounds__(256, 2) void k2_gemm(
    const u16* __restrict__ H4a, const u16* __restrict__ H4b,
    const u16* __restrict__ W5h, const u16* __restrict__ W5l,
    const int* __restrict__ sel,
    int P, int TPS, int S,
    float* __restrict__ pmax, int* __restrict__ pidx)
{
  __shared__ u16 As[128 * 136];
  __shared__ float redM[1024];
  __shared__ int   redI[1024];

  const int nc = blockIdx.x;   // channel chunk fastest -> L2 reuse of A tiles
  const int s  = blockIdx.y;
  const int b  = blockIdx.z;
  const int tid = threadIdx.x;
  const int lane = tid & 63;
  const int w = tid >> 6;
  const int wm = w >> 1, wn = w & 1;
  const int l15 = lane & 15, quad = lane >> 4;

  // hoisted Bh fragments; Bl re-read per mt (L2-resident, 512 KB total)
  bf16x8 bh[4][4];
  int chbase[4];
  #pragma unroll
  for (int tn = 0; tn < 4; ++tn)
    chbase[tn] = (nc << 7) + wn * 64 + tn * 16 + l15;
  #pragma unroll
  for (int ks = 0; ks < 4; ++ks)
    #pragma unroll
    for (int tn = 0; tn < 4; ++tn)
      bh[ks][tn] = *(const bf16x8*)&W5h[(size_t)chbase[tn] * 128 + ks * 32 + (quad << 3)];

  float runM[4]; int runI[4];
  #pragma unroll
  for (int tn = 0; tn < 4; ++tn) { runM[tn] = -3.4e38f; runI[tn] = 0x7FFFFFFF; }

  const int nt  = (P + 127) >> 7;
  const int mt0 = s * TPS;
  const int mt1 = min(mt0 + TPS, nt);
  const f32x4 vzero = {0.f, 0.f, 0.f, 0.f};

  for (int mt = mt0; mt < mt1; ++mt) {
    const int mb = mt << 7;
    f32x4 acc[4][4];
    #pragma unroll
    for (int tm = 0; tm < 4; ++tm)
      #pragma unroll
      for (int tn = 0; tn < 4; ++tn)
        acc[tm][tn] = vzero;

    // ---- stage Ah
    __syncthreads();
    k2_stage(As, H4a, sel, b, mb, P, tid);
    __syncthreads();

    // sweep 1: Ah x Bh
    #pragma unroll
    for (int ks = 0; ks < 4; ++ks) {
      bf16x8 af[4];
      #pragma unroll
      for (int tm = 0; tm < 4; ++tm)
        af[tm] = *(const bf16x8*)&As[(wm * 64 + tm * 16 + l15) * 136 + ks * 32 + (quad << 3)];
      #pragma unroll
      for (int tm = 0; tm < 4; ++tm)
        #pragma unroll
        for (int tn = 0; tn < 4; ++tn)
          acc[tm][tn] = __builtin_amdgcn_mfma_f32_16x16x32_bf16(
              af[tm], bh[ks][tn], acc[tm][tn], 0, 0, 0);
    }
    // sweep 2: Ah x Bl
    #pragma unroll
    for (int ks = 0; ks < 4; ++ks) {
      bf16x8 bl[4];
      #pragma unroll
      for (int tn = 0; tn < 4; ++tn)
        bl[tn] = *(const bf16x8*)&W5l[(size_t)chbase[tn] * 128 + ks * 32 + (quad << 3)];
      bf16x8 af[4];
      #pragma unroll
      for (int tm = 0; tm < 4; ++tm)
        af[tm] = *(const bf16x8*)&As[(wm * 64 + tm * 16 + l15) * 136 + ks * 32 + (quad << 3)];
      #pragma unroll
      for (int tm = 0; tm < 4; ++tm)
        #pragma unroll
        for (int tn = 0; tn < 4; ++tn)
          acc[tm][tn] = __builtin_amdgcn_mfma_f32_16x16x32_bf16(
              af[tm], bl[tn], acc[tm][tn], 0, 0, 0);
    }

    // ---- stage Al
    __syncthreads();
    k2_stage(As, H4b, sel, b, mb, P, tid);
    __syncthreads();

    // sweep 3: Al x Bh
    #pragma unroll
    for (int ks = 0; ks < 4; ++ks) {
      bf16x8 af[4];
      #pragma unroll
      for (int tm = 0; tm < 4; ++tm)
        af[tm] = *(const bf16x8*)&As[(wm * 64 + tm * 16 + l15) * 136 + ks * 32 + (quad << 3)];
      #pragma unroll
      for (int tm = 0; tm < 4; ++tm)
        #pragma unroll
        for (int tn = 0; tn < 4; ++tn)
          acc[tm][tn] = __builtin_amdgcn_mfma_f32_16x16x32_bf16(
              af[tm], bh[ks][tn], acc[tm][tn], 0, 0, 0);
    }

    // epilogue: running (max, first idx); C layout col=lane&15 (ch), row=quad*4+r (pt)
    #pragma unroll
    for (int tm = 0; tm < 4; ++tm) {
      int ptb = mb + wm * 64 + tm * 16 + (quad << 2);
      #pragma unroll
      for (int r = 0; r < 4; ++r) {
        int pt = ptb + r;
        bool ok = (pt < P);
        #pragma unroll
        for (int tn = 0; tn < 4; ++tn) {
          float v = acc[tm][tn][r];
          if (ok && (v > runM[tn] || (v == runM[tn] && pt < runI[tn]))) {
            runM[tn] = v; runI[tn] = pt;
          }
        }
      }
    }
  }

  // cross-wave reduction: slot = wm*4 + quad
  #pragma unroll
  for (int tn = 0; tn < 4; ++tn) {
    int chl  = wn * 64 + tn * 16 + l15;
    int slot = (wm << 2) + quad;
    redM[(chl << 3) + slot] = runM[tn];
    redI[(chl << 3) + slot] = runI[tn];
  }
  __syncthreads();
  if (tid < 128) {
    float bm = redM[tid << 3]; int bi = redI[tid << 3];
    #pragma unroll
    for (int s2 = 1; s2 < 8; ++s2) {
      float v = redM[(tid << 3) + s2]; int ii = redI[(tid << 3) + s2];
      if (v > bm || (v == bm && ii < bi)) { bm = v; bi = ii; }
    }
    size_t o = ((size_t)b * 1024 + (nc << 7) + tid) * (size_t)S + s;
    pmax[o] = bm; pidx[o] = bi;
  }
}

// ---------------------------------------------------------------------------
// K3: reduce partials -> per-channel argmax (BN sign test), mark used bitmap,
// prefix-select first 600 zero-count indices (stable-argsort semantics).
// ---------------------------------------------------------------------------
__global__ __launch_bounds__(256) void k3_select(
    const float* __restrict__ pmax, const int* __restrict__ pidx,
    const float* __restrict__ g5, const float* __restrict__ b5,
    const float* __restrict__ m5, const float* __restrict__ v5,
    int* __restrict__ sel)
{
  __shared__ unsigned char used[8192];
  __shared__ int cnts[256];
  __shared__ int pref[256];
  const int b = blockIdx.x, tid = threadIdx.x;

  #pragma unroll
  for (int i = 0; i < 8; ++i) ((int*)used)[i * 256 + tid] = 0;
  __syncthreads();

  for (int ch = tid; ch < 1024; ch += 256) {
    const float* pm = pmax + (((size_t)b << 10) + ch) * 8;
    const int*   pi = pidx + (((size_t)b << 10) + ch) * 8;
    float bm = pm[0]; int bi = pi[0];
    #pragma unroll
    for (int s2 = 1; s2 < 8; ++s2) {
      float v = pm[s2]; int ii = pi[s2];
      if (v > bm || (v == bm && ii < bi)) { bm = v; bi = ii; }
    }
    float s5 = g5[ch] / sqrtf(v5[ch] + EPSBN);
    float z = fmaf(bm, s5, b5[ch] - m5[ch] * s5);
    int idx = (z > 0.f) ? (bi & 8191) : 0;  // all-nonpositive channel -> argmax 0
    used[idx] = 1;
  }
  __syncthreads();

  const int base = tid << 5;
  int c = 0;
  #pragma unroll
  for (int i = 0; i < 32; ++i) c += (used[base + i] == 0) ? 1 : 0;
  cnts[tid] = c;
  __syncthreads();
  if (tid == 0) {
    int r = 0;
    for (int i = 0; i < 256; ++i) { pref[i] = r; r += cnts[i]; }
  }
  __syncthreads();
  int rank = pref[tid];
  for (int i = 0; i < 32; ++i) {
    int n0 = base + i;
    if (!used[n0]) { if (rank < 600) sel[b * 600 + rank] = n0; ++rank; }
  }
}

// ---------------------------------------------------------------------------
// K6: pooled = relu(bn5(max over S=2 partials)); fc1+bn6+relu; fc2 -> logits.
// ---------------------------------------------------------------------------
__global__ __launch_bounds__(512) void k6_fc(
    const float* __restrict__ pmax2,
    const float* __restrict__ g5, const float* __restrict__ b5,
    const float* __restrict__ m5, const float* __restrict__ v5,
    const float* __restrict__ L1w,
    const float* __restrict__ g6, const float* __restrict__ b6,
    const float* __restrict__ m6, const float* __restrict__ v6,
    const float* __restrict__ L2w, const float* __restrict__ L2b,
    float* __restrict__ out)
{
  __shared__ float pooled[1024];
  __shared__ float h6[512];
  const int b = blockIdx.x, tid = threadIdx.x;

  for (int ch = tid; ch < 1024; ch += 512) {
    const float* pm = pmax2 + (((size_t)b << 10) + ch) * 2;
    float raw = fmaxf(pm[0], pm[1]);
    float s5 = g5[ch] / sqrtf(v5[ch] + EPSBN);
    pooled[ch] = fmaxf(0.f, fmaf(raw, s5, b5[ch] - m5[ch] * s5));
  }
  __syncthreads();

  {
    const int o = tid;
    float a0 = 0.f, a1 = 0.f, a2 = 0.f, a3 = 0.f;
    for (int j = 0; j < 1024; j += 8) {
      float4 w0 = *(const float4*)&L1w[(size_t)o * 1024 + j];
      float4 w1 = *(const float4*)&L1w[(size_t)o * 1024 + j + 4];
      float4 p0 = *(const float4*)&pooled[j];
      float4 p1 = *(const float4*)&pooled[j + 4];
      a0 = fmaf(w0.x, p0.x, a0); a1 = fmaf(w0.y, p0.y, a1);
      a2 = fmaf(w0.z, p0.z, a2); a3 = fmaf(w0.w, p0.w, a3);
      a0 = fmaf(w1.x, p1.x, a0); a1 = fmaf(w1.y, p1.y, a1);
      a2 = fmaf(w1.z, p1.z, a2); a3 = fmaf(w1.w, p1.w, a3);
    }
    float acc = (a0 + a1) + (a2 + a3);
    float s6 = g6[o] / sqrtf(v6[o] + EPSBN);
    h6[o] = fmaxf(0.f, fmaf(acc, s6, b6[o] - m6[o] * s6));
  }
  __syncthreads();

  if (tid < 40) {
    float acc = L2b[tid];
    for (int j = 0; j < 512; j += 4) {
      float4 wv = *(const float4*)&L2w[(size_t)tid * 512 + j];
      acc = fmaf(wv.x, h6[j + 0], acc);
      acc = fmaf(wv.y, h6[j + 1], acc);
      acc = fmaf(wv.z, h6[j + 2], acc);
      acc = fmaf(wv.w, h6[j + 3], acc);
    }
    out[b * 40 + tid] = acc;
  }
}

// ---------------------------------------------------------------------------
// launcher
// ---------------------------------------------------------------------------
extern "C" void kernel_launch(void* const* d_in, const int* in_sizes, int n_in,
                              void* d_out, int out_size, void* d_ws, size_t ws_size,
                              hipStream_t stream)
{
  (void)in_sizes; (void)n_in; (void)out_size; (void)ws_size;
  const float* x   = (const float*)d_in[0];
  const float* W1  = (const float*)d_in[1];
  const float* g1  = (const float*)d_in[2];
  const float* b1  = (const float*)d_in[3];
  const float* m1  = (const float*)d_in[4];
  const float* v1  = (const float*)d_in[5];
  const float* W2  = (const float*)d_in[6];
  const float* g2  = (const float*)d_in[7];
  const float* b2  = (const float*)d_in[8];
  const float* m2  = (const float*)d_in[9];
  const float* v2  = (const float*)d_in[10];
  const float* W3  = (const float*)d_in[11];
  const float* g3  = (const float*)d_in[12];
  const float* b3  = (const float*)d_in[13];
  const float* m3  = (const float*)d_in[14];
  const float* v3  = (const float*)d_in[15];
  const float* W4  = (const float*)d_in[16];
  const float* g4  = (const float*)d_in[17];
  const float* b4  = (const float*)d_in[18];
  const float* m4  = (const float*)d_in[19];
  const float* v4  = (const float*)d_in[20];
  const float* W5  = (const float*)d_in[21];
  const float* g5  = (const float*)d_in[22];
  const float* b5  = (const float*)d_in[23];
  const float* m5  = (const float*)d_in[24];
  const float* v5  = (const float*)d_in[25];
  const float* L1w = (const float*)d_in[26];
  const float* g6  = (const float*)d_in[27];
  const float* b6  = (const float*)d_in[28];
  const float* m6  = (const float*)d_in[29];
  const float* v6  = (const float*)d_in[30];
  const float* L2w = (const float*)d_in[31];
  const float* L2b = (const float*)d_in[32];

  char* ws = (char*)d_ws;
  float* Wf    = (float*)(ws + 0);            // 2,560 B (pad to 4,096)
  u16*   W5h   = (u16*)(ws + 4096);           // 262,144 B
  u16*   W5l   = (u16*)(ws + 266240);         // 262,144 B
  u16*   H4a   = (u16*)(ws + 528384);         // 33,554,432 B
  u16*   H4b   = (u16*)(ws + 34082816);       // 33,554,432 B
  float* pmax  = (float*)(ws + 67637248);     // 524,288 B
  int*   pidx  = (int*)(ws + 68161536);       // 524,288 B
  int*   sel   = (int*)(ws + 68685824);       // 38,400 B
  float* pmax2 = (float*)(ws + 68724224);     // 131,072 B
  int*   pidx2 = (int*)(ws + 68855296);       // 131,072 B
  // total ~= 65.8 MB

  k0_prep<<<514, 256, 0, stream>>>(W5,
                                   g1, b1, m1, v1, g2, b2, m2, v2,
                                   g3, b3, m3, v3, g4, b4, m4, v4,
                                   W5h, W5l, Wf);
  k1_conv<<<1024, 128, 0, stream>>>(x, W1, W2, W3, W4, Wf, H4a, H4b);
  k2_gemm<<<dim3(8, 8, 16), 256, 0, stream>>>(H4a, H4b, W5h, W5l, nullptr,
                                              8192, 8, 8, pmax, pidx);
  k3_select<<<16, 256, 0, stream>>>(pmax, pidx, g5, b5, m5, v5, sel);
  k2_gemm<<<dim3(8, 2, 16), 256, 0, stream>>>(H4a, H4b, W5h, W5l, sel,
                                              600, 3, 2, pmax2, pidx2);
  k6_fc<<<16, 512, 0, stream>>>(pmax2, g5, b5, m5, v5, L1w,
                                g6, b6, m6, v6, L2w, L2b, (float*)d_out);
}

// Round 3
// 611.378 us; speedup vs baseline: 1.3025x; 1.3025x over previous
//
#include <hip/hip_runtime.h>
#include <cstdint>

typedef uint16_t u16;
typedef __attribute__((ext_vector_type(8))) short bf16x8;
typedef __attribute__((ext_vector_type(4))) float f32x4;

#define EPSBN 1e-5f

__device__ __forceinline__ float bf2f(u16 h) {
  return __uint_as_float(((unsigned)h) << 16);
}
__device__ __forceinline__ u16 f2bf(float f) {
  unsigned u = __float_as_uint(f);
  unsigned r = u + 0x7fffu + ((u >> 16) & 1u);
  return (u16)(r >> 16);
}

// ---------------------------------------------------------------------------
// K0: split W5 into bf16 hi/lo; transpose W2/W3/W4; copy W1; fold BN 1..4.
// Wf floats: Wt2@0[j*64+o](4096) Wt3@4096 Wt4@8192[j*128+o](8192)
//            W1@16384(192) scale@16576(320: L1 0-63,L2 64-127,L3 128-191,
//            L4 192-319) shift@16896(320)
// ---------------------------------------------------------------------------
__global__ void k0_prep(const float* __restrict__ W5,
                        const float* __restrict__ W1, const float* __restrict__ W2,
                        const float* __restrict__ W3, const float* __restrict__ W4,
                        const float* g1, const float* b1, const float* m1, const float* v1,
                        const float* g2, const float* b2, const float* m2, const float* v2,
                        const float* g3, const float* b3, const float* m3, const float* v3,
                        const float* g4, const float* b4, const float* m4, const float* v4,
                        u16* __restrict__ W5h, u16* __restrict__ W5l,
                        float* __restrict__ Wf)
{
  int idx = blockIdx.x * 256 + threadIdx.x;
  if (idx < 131072) {
    float w = W5[idx];
    u16 hi = f2bf(w);
    W5h[idx] = hi;
    W5l[idx] = f2bf(w - bf2f(hi));
    return;
  }
  int j = idx - 131072;
  if (j < 4096) {                       // Wt2[j2*64+o] = W2[o*64+j2]
    Wf[j] = W2[(j & 63) * 64 + (j >> 6)];
  } else if (j < 8192) {
    int t = j - 4096;
    Wf[j] = W3[(t & 63) * 64 + (t >> 6)];
  } else if (j < 16384) {               // Wt4[j4*128+o] = W4[o*64+j4]
    int t = j - 8192;
    Wf[j] = W4[(t & 127) * 64 + (t >> 7)];
  } else if (j < 16576) {
    Wf[j] = W1[j - 16384];
  } else if (j < 16896) {
    int t = j - 16576;
    const float *g, *bb, *mm, *vv; int ch;
    if (t < 64)       { g = g1; bb = b1; mm = m1; vv = v1; ch = t;       }
    else if (t < 128) { g = g2; bb = b2; mm = m2; vv = v2; ch = t - 64;  }
    else if (t < 192) { g = g3; bb = b3; mm = m3; vv = v3; ch = t - 128; }
    else              { g = g4; bb = b4; mm = m4; vv = v4; ch = t - 192; }
    float s = g[ch] / sqrtf(vv[ch] + EPSBN);
    Wf[16576 + t] = s;
    Wf[16896 + t] = bb[ch] - mm[ch] * s;
  }
}

// ---------------------------------------------------------------------------
// K1: layers 1-4, one point per thread. h lives in LDS hs[ch][tid] (thread-
// private column, no barriers, 2-way-free banks); accumulators in statically
// indexed registers; weights via wave-uniform loads of transposed rows
// (s_load path). Output: h4 split hi/lo bf16, layout [b][kg(=ch/8)][n][8]
// -> fully coalesced 16B stores.
// ---------------------------------------------------------------------------
__global__ __launch_bounds__(128, 2) void k1_conv(
    const float* __restrict__ x, const float* __restrict__ Wf,
    u16* __restrict__ H4a, u16* __restrict__ H4b)
{
  __shared__ float hs[64][132];
  const int tid = threadIdx.x;
  const int pid = blockIdx.x * 128 + tid;
  const int b = pid >> 13, n = pid & 8191;

  const float* __restrict__ Wt2 = Wf;
  const float* __restrict__ Wt3 = Wf + 4096;
  const float* __restrict__ Wt4 = Wf + 8192;
  const float* __restrict__ W1  = Wf + 16384;
  const float* __restrict__ SC  = Wf + 16576;
  const float* __restrict__ SH  = Wf + 16896;

  const float x0 = x[(b * 3 + 0) * 8192 + n];
  const float x1 = x[(b * 3 + 1) * 8192 + n];
  const float x2 = x[(b * 3 + 2) * 8192 + n];

  // L1 (3 -> 64)
  #pragma unroll
  for (int o = 0; o < 64; ++o) {
    float c = W1[o * 3] * x0;
    c = fmaf(W1[o * 3 + 1], x1, c);
    c = fmaf(W1[o * 3 + 2], x2, c);
    hs[o][tid] = fmaxf(0.f, fmaf(c, SC[o], SH[o]));
  }

  // L2 (64 -> 64)
  {
    float hn[64];
    #pragma unroll
    for (int o = 0; o < 64; ++o) hn[o] = 0.f;
    #pragma unroll 2
    for (int j = 0; j < 64; ++j) {
      float hj = hs[j][tid];
      const float* __restrict__ wr = &Wt2[j * 64];
      #pragma unroll
      for (int o = 0; o < 64; ++o) hn[o] = fmaf(wr[o], hj, hn[o]);
    }
    #pragma unroll
    for (int o = 0; o < 64; ++o)
      hs[o][tid] = fmaxf(0.f, fmaf(hn[o], SC[64 + o], SH[64 + o]));
  }

  // L3 (64 -> 64)
  {
    float hn[64];
    #pragma unroll
    for (int o = 0; o < 64; ++o) hn[o] = 0.f;
    #pragma unroll 2
    for (int j = 0; j < 64; ++j) {
      float hj = hs[j][tid];
      const float* __restrict__ wr = &Wt3[j * 64];
      #pragma unroll
      for (int o = 0; o < 64; ++o) hn[o] = fmaf(wr[o], hj, hn[o]);
    }
    #pragma unroll
    for (int o = 0; o < 64; ++o)
      hs[o][tid] = fmaxf(0.f, fmaf(hn[o], SC[128 + o], SH[128 + o]));
  }

  // L4 (64 -> 128) + BN/relu + hi/lo split + coalesced store
  {
    float h4[128];
    #pragma unroll
    for (int o = 0; o < 128; ++o) h4[o] = 0.f;
    for (int j = 0; j < 64; ++j) {
      float hj = hs[j][tid];
      const float* __restrict__ wr = &Wt4[j * 128];
      #pragma unroll
      for (int o = 0; o < 128; ++o) h4[o] = fmaf(wr[o], hj, h4[o]);
    }
    #pragma unroll
    for (int o = 0; o < 128; ++o)
      h4[o] = fmaxf(0.f, fmaf(h4[o], SC[192 + o], SH[192 + o]));

    #pragma unroll
    for (int o8 = 0; o8 < 16; ++o8) {
      unsigned hv[4], lv[4];
      #pragma unroll
      for (int p = 0; p < 4; ++p) {
        float v0 = h4[o8 * 8 + 2 * p];
        float v1 = h4[o8 * 8 + 2 * p + 1];
        u16 a0 = f2bf(v0), a1 = f2bf(v1);
        float e0 = v0 - bf2f(a0), e1 = v1 - bf2f(a1);
        hv[p] = (unsigned)a0 | ((unsigned)a1 << 16);
        lv[p] = (unsigned)f2bf(e0) | ((unsigned)f2bf(e1) << 16);
      }
      uint4 ha, la;
      ha.x = hv[0]; ha.y = hv[1]; ha.z = hv[2]; ha.w = hv[3];
      la.x = lv[0]; la.y = lv[1]; la.z = lv[2]; la.w = lv[3];
      size_t e = ((size_t)(b * 16 + o8) * 8192 + n) * 8;
      *(uint4*)&H4a[e] = ha;
      *(uint4*)&H4b[e] = la;
    }
  }
}

// ---------------------------------------------------------------------------
// K2: C[pt][ch] = sum_k h4[pt][k]*W5[ch][k], exact via Ah*Bh + Ah*Bl + Al*Bh.
// One 128-pt tile staged ONCE per block (Ah+Al LDS resident, afh hoisted to
// regs); internal loop over all 8 channel chunks with B-frags streamed from
// L2. Per-chunk argmax partials written per tile (S = #tiles).
// ---------------------------------------------------------------------------
__global__ __launch_bounds__(256, 2) void k2_gemm(
    const u16* __restrict__ H4a, const u16* __restrict__ H4b,
    const u16* __restrict__ W5h, const u16* __restrict__ W5l,
    const int* __restrict__ sel,
    int P, int S,
    float* __restrict__ pmax, int* __restrict__ pidx)
{
  __shared__ u16 Ah[128 * 136];
  __shared__ u16 Al[128 * 136];
  __shared__ float redM[1024];
  __shared__ int   redI[1024];

  const int s = blockIdx.x;     // point tile
  const int b = blockIdx.y;
  const int tid = threadIdx.x;
  const int lane = tid & 63, w = tid >> 6;
  const int wm = w >> 1, wn = w & 1;
  const int l15 = lane & 15, quad = lane >> 4;
  const int mb = s << 7;

  // stage Ah + Al (coalesced: layout [b][kg][n][8], lanes span n)
  #pragma unroll
  for (int i = 0; i < 8; ++i) {
    int f = (i << 8) + tid;
    int kg = f >> 7, p = f & 127;
    int pt = mb + p;
    uint4 va; va.x = va.y = va.z = va.w = 0u;
    uint4 vb; vb.x = vb.y = vb.z = vb.w = 0u;
    int n0 = pt;
    bool ok = true;
    if (sel) { ok = (pt < P); n0 = ok ? (sel[b * 600 + pt] & 8191) : 0; }
    if (ok) {
      size_t e = ((size_t)(b * 16 + kg) * 8192 + n0) * 8;
      va = *(const uint4*)&H4a[e];
      vb = *(const uint4*)&H4b[e];
    }
    *(uint4*)&Ah[p * 136 + kg * 8] = va;
    *(uint4*)&Al[p * 136 + kg * 8] = vb;
  }
  __syncthreads();

  // hoist Ah fragments (nc-invariant)
  bf16x8 afh[4][4];
  #pragma unroll
  for (int ks = 0; ks < 4; ++ks)
    #pragma unroll
    for (int tm = 0; tm < 4; ++tm)
      afh[ks][tm] = *(const bf16x8*)&Ah[(wm * 64 + tm * 16 + l15) * 136 + ks * 32 + quad * 8];

  const f32x4 vzero = {0.f, 0.f, 0.f, 0.f};

  for (int nc = 0; nc < 8; ++nc) {
    f32x4 acc[4][4];
    #pragma unroll
    for (int tm = 0; tm < 4; ++tm)
      #pragma unroll
      for (int tn = 0; tn < 4; ++tn)
        acc[tm][tn] = vzero;

    #pragma unroll
    for (int ks = 0; ks < 4; ++ks) {
      bf16x8 bh[4], bl[4], aflk[4];
      #pragma unroll
      for (int tn = 0; tn < 4; ++tn) {
        size_t cb = (size_t)(nc * 128 + wn * 64 + tn * 16 + l15) * 128 + ks * 32 + quad * 8;
        bh[tn] = *(const bf16x8*)&W5h[cb];
        bl[tn] = *(const bf16x8*)&W5l[cb];
      }
      #pragma unroll
      for (int tm = 0; tm < 4; ++tm)
        aflk[tm] = *(const bf16x8*)&Al[(wm * 64 + tm * 16 + l15) * 136 + ks * 32 + quad * 8];
      #pragma unroll
      for (int tm = 0; tm < 4; ++tm)
        #pragma unroll
        for (int tn = 0; tn < 4; ++tn) {
          acc[tm][tn] = __builtin_amdgcn_mfma_f32_16x16x32_bf16(afh[ks][tm], bh[tn], acc[tm][tn], 0, 0, 0);
          acc[tm][tn] = __builtin_amdgcn_mfma_f32_16x16x32_bf16(afh[ks][tm], bl[tn], acc[tm][tn], 0, 0, 0);
          acc[tm][tn] = __builtin_amdgcn_mfma_f32_16x16x32_bf16(aflk[tm],   bh[tn], acc[tm][tn], 0, 0, 0);
        }
    }

    // epilogue: per-channel (max, first idx) for this chunk
    float rM[4]; int rI[4];
    #pragma unroll
    for (int tn = 0; tn < 4; ++tn) { rM[tn] = -3.4e38f; rI[tn] = 0x7FFFFFFF; }
    #pragma unroll
    for (int tm = 0; tm < 4; ++tm) {
      int ptb = mb + wm * 64 + tm * 16 + (quad << 2);
      #pragma unroll
      for (int r = 0; r < 4; ++r) {
        int pt = ptb + r;
        bool ok = (pt < P);
        #pragma unroll
        for (int tn = 0; tn < 4; ++tn) {
          float v = acc[tm][tn][r];
          if (ok && (v > rM[tn] || (v == rM[tn] && pt < rI[tn]))) { rM[tn] = v; rI[tn] = pt; }
        }
      }
    }
    #pragma unroll
    for (int tn = 0; tn < 4; ++tn) {
      int chl  = wn * 64 + tn * 16 + l15;
      int slot = (wm << 2) + quad;
      redM[(chl << 3) + slot] = rM[tn];
      redI[(chl << 3) + slot] = rI[tn];
    }
    __syncthreads();
    if (tid < 128) {
      float bm = redM[tid << 3]; int bi = redI[tid << 3];
      #pragma unroll
      for (int s2 = 1; s2 < 8; ++s2) {
        float v = redM[(tid << 3) + s2]; int ii = redI[(tid << 3) + s2];
        if (v > bm || (v == bm && ii < bi)) { bm = v; bi = ii; }
      }
      size_t o = ((size_t)b * 1024 + nc * 128 + tid) * (size_t)S + s;
      pmax[o] = bm; pidx[o] = bi;
    }
    __syncthreads();
  }
}

// ---------------------------------------------------------------------------
// K3: reduce S=64 tile-partials -> per-channel argmax (BN sign test), mark
// used bitmap, prefix-select first 600 zero-count indices.
// ---------------------------------------------------------------------------
__global__ __launch_bounds__(256) void k3_select(
    const float* __restrict__ pmax, const int* __restrict__ pidx,
    const float* __restrict__ g5, const float* __restrict__ b5,
    const float* __restrict__ m5, const float* __restrict__ v5,
    int* __restrict__ sel)
{
  __shared__ unsigned char used[8192];
  __shared__ int cnts[256];
  __shared__ int pref[256];
  const int b = blockIdx.x, tid = threadIdx.x;

  #pragma unroll
  for (int i = 0; i < 8; ++i) ((int*)used)[i * 256 + tid] = 0;
  __syncthreads();

  for (int ch = tid; ch < 1024; ch += 256) {
    const float* pm = pmax + (((size_t)b << 10) + ch) * 64;
    const int*   pi = pidx + (((size_t)b << 10) + ch) * 64;
    float bm = pm[0]; int bi = pi[0];
    for (int s2 = 1; s2 < 64; ++s2) {
      float v = pm[s2]; int ii = pi[s2];
      if (v > bm || (v == bm && ii < bi)) { bm = v; bi = ii; }
    }
    float s5 = g5[ch] / sqrtf(v5[ch] + EPSBN);
    float z = fmaf(bm, s5, b5[ch] - m5[ch] * s5);
    int idx = (z > 0.f) ? (bi & 8191) : 0;   // all-nonpositive channel -> 0
    used[idx] = 1;
  }
  __syncthreads();

  const int base = tid << 5;
  int c = 0;
  #pragma unroll
  for (int i = 0; i < 32; ++i) c += (used[base + i] == 0) ? 1 : 0;
  cnts[tid] = c;
  __syncthreads();
  if (tid == 0) {
    int r = 0;
    for (int i = 0; i < 256; ++i) { pref[i] = r; r += cnts[i]; }
  }
  __syncthreads();
  int rank = pref[tid];
  for (int i = 0; i < 32; ++i) {
    int n0 = base + i;
    if (!used[n0]) { if (rank < 600) sel[b * 600 + rank] = n0; ++rank; }
  }
}

// ---------------------------------------------------------------------------
// K6: pooled = relu(bn5(max over S=5 partials)); fc1+bn6+relu; fc2 -> logits.
// ---------------------------------------------------------------------------
__global__ __launch_bounds__(512) void k6_fc(
    const float* __restrict__ pmax2,
    const float* __restrict__ g5, const float* __restrict__ b5,
    const float* __restrict__ m5, const float* __restrict__ v5,
    const float* __restrict__ L1w,
    const float* __restrict__ g6, const float* __restrict__ b6,
    const float* __restrict__ m6, const float* __restrict__ v6,
    const float* __restrict__ L2w, const float* __restrict__ L2b,
    float* __restrict__ out)
{
  __shared__ float pooled[1024];
  __shared__ float h6[512];
  const int b = blockIdx.x, tid = threadIdx.x;

  for (int ch = tid; ch < 1024; ch += 512) {
    const float* pm = pmax2 + (((size_t)b << 10) + ch) * 5;
    float raw = pm[0];
    #pragma unroll
    for (int s2 = 1; s2 < 5; ++s2) raw = fmaxf(raw, pm[s2]);
    float s5 = g5[ch] / sqrtf(v5[ch] + EPSBN);
    pooled[ch] = fmaxf(0.f, fmaf(raw, s5, b5[ch] - m5[ch] * s5));
  }
  __syncthreads();

  {
    const int o = tid;
    float a0 = 0.f, a1 = 0.f, a2 = 0.f, a3 = 0.f;
    for (int j = 0; j < 1024; j += 8) {
      float4 w0 = *(const float4*)&L1w[(size_t)o * 1024 + j];
      float4 w1 = *(const float4*)&L1w[(size_t)o * 1024 + j + 4];
      float4 p0 = *(const float4*)&pooled[j];
      float4 p1 = *(const float4*)&pooled[j + 4];
      a0 = fmaf(w0.x, p0.x, a0); a1 = fmaf(w0.y, p0.y, a1);
      a2 = fmaf(w0.z, p0.z, a2); a3 = fmaf(w0.w, p0.w, a3);
      a0 = fmaf(w1.x, p1.x, a0); a1 = fmaf(w1.y, p1.y, a1);
      a2 = fmaf(w1.z, p1.z, a2); a3 = fmaf(w1.w, p1.w, a3);
    }
    float acc = (a0 + a1) + (a2 + a3);
    float s6 = g6[o] / sqrtf(v6[o] + EPSBN);
    h6[o] = fmaxf(0.f, fmaf(acc, s6, b6[o] - m6[o] * s6));
  }
  __syncthreads();

  if (tid < 40) {
    float acc = L2b[tid];
    for (int j = 0; j < 512; j += 4) {
      float4 wv = *(const float4*)&L2w[(size_t)tid * 512 + j];
      acc = fmaf(wv.x, h6[j + 0], acc);
      acc = fmaf(wv.y, h6[j + 1], acc);
      acc = fmaf(wv.z, h6[j + 2], acc);
      acc = fmaf(wv.w, h6[j + 3], acc);
    }
    out[b * 40 + tid] = acc;
  }
}

// ---------------------------------------------------------------------------
// launcher
// ---------------------------------------------------------------------------
extern "C" void kernel_launch(void* const* d_in, const int* in_sizes, int n_in,
                              void* d_out, int out_size, void* d_ws, size_t ws_size,
                              hipStream_t stream)
{
  (void)in_sizes; (void)n_in; (void)out_size; (void)ws_size;
  const float* x   = (const float*)d_in[0];
  const float* W1  = (const float*)d_in[1];
  const float* g1  = (const float*)d_in[2];
  const float* b1  = (const float*)d_in[3];
  const float* m1  = (const float*)d_in[4];
  const float* v1  = (const float*)d_in[5];
  const float* W2  = (const float*)d_in[6];
  const float* g2  = (const float*)d_in[7];
  const float* b2  = (const float*)d_in[8];
  const float* m2  = (const float*)d_in[9];
  const float* v2  = (const float*)d_in[10];
  const float* W3  = (const float*)d_in[11];
  const float* g3  = (const float*)d_in[12];
  const float* b3  = (const float*)d_in[13];
  const float* m3  = (const float*)d_in[14];
  const float* v3  = (const float*)d_in[15];
  const float* W4  = (const float*)d_in[16];
  const float* g4  = (const float*)d_in[17];
  const float* b4  = (const float*)d_in[18];
  const float* m4  = (const float*)d_in[19];
  const float* v4  = (const float*)d_in[20];
  const float* W5  = (const float*)d_in[21];
  const float* g5  = (const float*)d_in[22];
  const float* b5  = (const float*)d_in[23];
  const float* m5  = (const float*)d_in[24];
  const float* v5  = (const float*)d_in[25];
  const float* L1w = (const float*)d_in[26];
  const float* g6  = (const float*)d_in[27];
  const float* b6  = (const float*)d_in[28];
  const float* m6  = (const float*)d_in[29];
  const float* v6  = (const float*)d_in[30];
  const float* L2w = (const float*)d_in[31];
  const float* L2b = (const float*)d_in[32];

  char* ws = (char*)d_ws;
  float* Wf    = (float*)(ws + 0);            // 68,864 B -> pad 69,632
  u16*   W5h   = (u16*)(ws + 69632);          // 262,144 B
  u16*   W5l   = (u16*)(ws + 331776);         // 262,144 B
  u16*   H4a   = (u16*)(ws + 593920);         // 33,554,432 B
  u16*   H4b   = (u16*)(ws + 34148352);       // 33,554,432 B
  float* pmax  = (float*)(ws + 67702784);     // 4,194,304 B
  int*   pidx  = (int*)(ws + 71897088);       // 4,194,304 B
  int*   sel   = (int*)(ws + 76091392);       // 38,400 B
  float* pmax2 = (float*)(ws + 76129792);     // 327,680 B
  int*   pidx2 = (int*)(ws + 76457472);       // 327,680 B
  // total ~76.8 MB

  k0_prep<<<578, 256, 0, stream>>>(W5, W1, W2, W3, W4,
                                   g1, b1, m1, v1, g2, b2, m2, v2,
                                   g3, b3, m3, v3, g4, b4, m4, v4,
                                   W5h, W5l, Wf);
  k1_conv<<<1024, 128, 0, stream>>>(x, Wf, H4a, H4b);
  k2_gemm<<<dim3(64, 16), 256, 0, stream>>>(H4a, H4b, W5h, W5l, nullptr,
                                            8192, 64, pmax, pidx);
  k3_select<<<16, 256, 0, stream>>>(pmax, pidx, g5, b5, m5, v5, sel);
  k2_gemm<<<dim3(5, 16), 256, 0, stream>>>(H4a, H4b, W5h, W5l, sel,
                                           600, 5, pmax2, pidx2);
  k6_fc<<<16, 512, 0, stream>>>(pmax2, g5, b5, m5, v5, L1w,
                                g6, b6, m6, v6, L2w, L2b, (float*)d_out);
}